// Round 7
// baseline (278.871 us; speedup 1.0000x reference)
//
#include <hip/hip_runtime.h>
#include <math.h>

#define BATCH 64
#define DIM   640
#define MSP   100        // spatial M = 10*10
#define BT    128        // block tile
#define NT2   5          // DIM / BT
#define NPAIR2 15        // NT2*(NT2+1)/2 upper-tri 128-tile pairs
#define NBLK2 960        // NPAIR2 * BATCH
#define PTRI  205120     // DIM*(DIM+1)/2
#define EPSV  1e-5f

// ws float-region offsets (floats)
#define WS_D 0
#define WS_S 40960
#define WS_G 81920            // 64 grand accumulators (raw sums)
#define WS_C 81984            // 64 per-batch arrival counters (uint)
// byte offsets (float region ends at 82048*4 = 328192, 256B-aligned)
#define XB_OFF 328192ull      // swizzled bf16 x: 2560 panels x 2048 shorts = 10,485,760 B
// total ws ~10.8 MB
//
// NOTE: cooperative launch is NOT usable in this harness (R3/R4: graph-capture
// breaks on hipLaunchCooperativeKernel / host-side queries). Plain launches.
//
// R7 structure: 2 kernels.
//   k_prep : x -> swizzled bf16 xb + norms + S/G/counter zero  (2560 blocks)
//   k_main : 960 blocks, ONE pass: phase 1 = 128-tile MFMA -> sqrt -> S/G
//            atomics (acc KEPT in registers); per-batch arrive+spin barrier
//            (all 15 blocks of a batch); phase 2 = centering from kept acc,
//            write triu fp32. Deletes k_write's full gram recompute + one
//            global launch/drain boundary; phase 2 unblocks per-batch.
//
// Spin-barrier safety:
//   - residency: grid 960 <= capacity 1024 (launch_bounds(256,4) -> VGPR<=128,
//     LDS 1KB, 16 waves/CU) -> all blocks co-resident -> no deadlock.
//   - coherence: arrival = __threadfence + release atomic add; waiters spin on
//     acquire loads; phase-2 S/G reads use agent-scope atomic loads (correct
//     even if blocks of one batch land on different XCDs).
//
// xb swizzle: panel = 16 rows x 128 k, stored [c = ks*4+lq][lm = row%16][8 halves].
// A wave's frag load (lanes lq=lane>>4, lm=lane&15) reads ONE contiguous
// 1024B block -> fully coalesced.
//
// XCD pinning heuristic: bid&7 = XCD; each XCD's 120 blocks serve 8 fixed
// batches (xb slice 1.28 MB < 4 MB per-XCD L2); perf-only, not correctness.

typedef __attribute__((ext_vector_type(8))) short short8;
typedef __attribute__((ext_vector_type(4))) float f32x4;

__device__ __forceinline__ short f2bf(float f) {
    union { float f; unsigned u; } x; x.f = f;
    unsigned r = x.u + 0x7fffu + ((x.u >> 16) & 1u);
    return (short)(r >> 16);
}
__device__ __forceinline__ float bf2f(short h) {
    union { unsigned u; float f; } x; x.u = ((unsigned)(unsigned short)h) << 16;
    return x.f;
}

// pair index u (0..14) -> (ti,tj) in 5x5 upper triangle
__device__ __forceinline__ void decode_pair5(int u, int& ti, int& tj) {
    ti = 0;
    while (u >= NT2 - ti) { u -= NT2 - ti; ++ti; }
    tj = ti + u;
}

// bid (0..959) -> (b, ti, tj) with XCD-pinned batches
__device__ __forceinline__ void decode_block128(int bid, int& b, int& ti, int& tj) {
    const int xcd = bid & 7;
    const int idx = bid >> 3;          // 0..119
    b = xcd + 8 * (idx & 7);           // fixed set of 8 batches per XCD
    decode_pair5(idx >> 3, ti, tj);    // 0..14
}

// One pass over x: bf16 RNE convert, K 100->128 zero-pad, store SWIZZLED xb;
// norms from ROUNDED values (diag d_i+d_i-2G_ii cancels exactly vs bf16 MFMA);
// zero S, G, and arrival counters (ws is poisoned each call).
__global__ __launch_bounds__(256) void k_prep(const float* __restrict__ x,
                                              float* __restrict__ ws) {
    short* xb = (short*)((char*)ws + XB_OFF);
    const int t = threadIdx.x;
    const int rr = t >> 4, c = t & 15;             // rr = row-in-panel, c = k-chunk
    const int row = blockIdx.x * 16 + rr;          // 0..40959
    const int k0 = c * 8;
    const float* src = x + (size_t)row * MSP;

    float v[8];
#pragma unroll
    for (int e = 0; e < 8; ++e) v[e] = 0.f;
    if (k0 <= 88) {                                // k0..k0+7 all < 100
        float4 u0 = *(const float4*)(src + k0);
        float4 u1 = *(const float4*)(src + k0 + 4);
        v[0] = u0.x; v[1] = u0.y; v[2] = u0.z; v[3] = u0.w;
        v[4] = u1.x; v[5] = u1.y; v[6] = u1.z; v[7] = u1.w;
    } else if (k0 == 96) {                         // only 96..99 valid (no OOB read)
        float4 u0 = *(const float4*)(src + 96);
        v[0] = u0.x; v[1] = u0.y; v[2] = u0.z; v[3] = u0.w;
    }

    short8 h; float s = 0.f;
#pragma unroll
    for (int e = 0; e < 8; ++e) {
        short hb = f2bf(v[e]);
        float vr = bf2f(hb);
        s += vr * vr;
        h[e] = hb;
    }
    // swizzled store: panel base + c*128 + rr*8
    *(short8*)(xb + (size_t)blockIdx.x * 2048 + c * 128 + rr * 8) = h;

    // norm reduce over the 16 k-chunks (lanes with same rr, c = lane&15)
    s += __shfl_xor(s, 1); s += __shfl_xor(s, 2);
    s += __shfl_xor(s, 4); s += __shfl_xor(s, 8);
    if (c == 0) { ws[WS_D + row] = s; ws[WS_S + row] = 0.f; }
    if (blockIdx.x == 0 && t < BATCH) {
        ws[WS_G + t] = 0.f;
        ((unsigned*)(ws + WS_C))[t] = 0u;
    }
}

// Fused gram pass: phase 1 sums (acc kept) -> per-batch spin barrier ->
// phase 2 centering + triu write from kept acc.
__global__ __launch_bounds__(256, 4) void k_main(const float* __restrict__ tsc,
                                                 float* __restrict__ ws,
                                                 float* __restrict__ out) {
    __shared__ float sRow[BT];
    __shared__ float sCol[BT];

    int b, ti, tj;
    decode_block128(blockIdx.x, b, ti, tj);
    const int i0 = ti * BT, j0 = tj * BT;
    const int tid = threadIdx.x;
    const short* xb = (const short*)((const char*)ws + XB_OFF);

    if (tid < BT) { sRow[tid] = 0.f; sCol[tid] = 0.f; }

    const int wave = tid >> 6, lane = tid & 63;
    const int lm = lane & 15, lq = lane >> 4;
    const int wr = wave >> 1, wc = wave & 1;
    const int r0 = wr * 64, c0 = wc * 64;

    // ---------------- phase 1: MFMA + sqrt sums ----------------
    const short* pa = xb + (size_t)(b * 40 + ((i0 + r0) >> 4)) * 2048 + lq * 128 + lm * 8;
    const short* pb = xb + (size_t)(b * 40 + ((j0 + c0) >> 4)) * 2048 + lq * 128 + lm * 8;

    f32x4 acc[4][4] = {};
#pragma unroll
    for (int ks = 0; ks < 4; ++ks) {
        short8 af[4], bf[4];
#pragma unroll
        for (int m = 0; m < 4; ++m) af[m] = *(const short8*)(pa + m * 2048 + ks * 512);
#pragma unroll
        for (int n = 0; n < 4; ++n) bf[n] = *(const short8*)(pb + n * 2048 + ks * 512);
#pragma unroll
        for (int m = 0; m < 4; ++m)
#pragma unroll
            for (int n = 0; n < 4; ++n)
                acc[m][n] = __builtin_amdgcn_mfma_f32_16x16x32_bf16(af[m], bf[n], acc[m][n], 0, 0, 0);
    }

    const float scale = expf(tsc[0]);
    const float* dn = ws + WS_D + b * DIM;
    float dj[4];
#pragma unroll
    for (int n = 0; n < 4; ++n) dj[n] = dn[j0 + c0 + 16 * n + lm];

    float rp[4][4] = {}, cp[4] = {};
#pragma unroll
    for (int m = 0; m < 4; ++m) {
        float di_[4];
#pragma unroll
        for (int r = 0; r < 4; ++r) di_[r] = dn[i0 + r0 + 16 * m + 4 * lq + r];
#pragma unroll
        for (int n = 0; n < 4; ++n)
#pragma unroll
            for (int p = 0; p < 4; ++p) {
                float v = __builtin_amdgcn_sqrtf(
                    fmaf(scale, fmaxf(fmaf(-2.f, acc[m][n][p], di_[p] + dj[n]), 0.f), EPSV));
                rp[m][p] += v; cp[n] += v;
            }
    }

    __syncthreads();   // sRow/sCol zero-init visible before LDS atomics
#pragma unroll
    for (int m = 0; m < 4; ++m)
#pragma unroll
        for (int p = 0; p < 4; ++p) {
            float v = rp[m][p];
            v += __shfl_xor(v, 1); v += __shfl_xor(v, 2);
            v += __shfl_xor(v, 4); v += __shfl_xor(v, 8);
            if (lm == 0) atomicAdd(&sRow[r0 + 16 * m + 4 * lq + p], v);
        }
#pragma unroll
    for (int n = 0; n < 4; ++n) {
        float v = cp[n];
        v += __shfl_xor(v, 16); v += __shfl_xor(v, 32);
        if (lq == 0) atomicAdd(&sCol[c0 + 16 * n + lm], v);
    }
    __syncthreads();

    float* S = ws + WS_S + b * DIM;
    if (tid < BT) {
        atomicAdd(&S[i0 + tid], sRow[tid]);
        if (ti != tj) atomicAdd(&S[j0 + tid], sCol[tid]);  // symmetry: col==row sums
        float gg = sRow[tid];                              // per-batch grand (raw)
        gg += __shfl_xor(gg, 1);  gg += __shfl_xor(gg, 2);  gg += __shfl_xor(gg, 4);
        gg += __shfl_xor(gg, 8);  gg += __shfl_xor(gg, 16); gg += __shfl_xor(gg, 32);
        if (lane == 0) atomicAdd(&ws[WS_G + b], (ti == tj ? 1.f : 2.f) * gg);
    }

    // ---------------- per-batch arrive + spin ----------------
    unsigned* cnt = (unsigned*)(ws + WS_C);
    __threadfence();            // drain this thread's global atomics (vmcnt 0)
    __syncthreads();            // all threads of block fenced
    if (tid == 0)
        __hip_atomic_fetch_add(cnt + b, 1u, __ATOMIC_RELEASE,
                               __HIP_MEMORY_SCOPE_AGENT);
    if (tid == 0) {
        while (__hip_atomic_load(cnt + b, __ATOMIC_ACQUIRE,
                                 __HIP_MEMORY_SCOPE_AGENT) < (unsigned)NPAIR2)
            __builtin_amdgcn_s_sleep(2);
    }
    __syncthreads();            // whole block sees batch-complete

    // ---------------- phase 2: centering + triu write from kept acc ----------------
    const bool diag = (ti == tj);
    if (diag && wr > wc) return;       // quadrant fully below diagonal
    const bool pred = diag && (wr == wc);

    const float inv = 1.f / (float)DIM;
    const float gmean = __hip_atomic_load(ws + WS_G + b, __ATOMIC_RELAXED,
                                          __HIP_MEMORY_SCOPE_AGENT) * (inv * inv);

    float bj[4]; int jj[4];
#pragma unroll
    for (int n = 0; n < 4; ++n) {
        int j = j0 + c0 + 16 * n + lm;
        jj[n] = j;
        bj[n] = -__hip_atomic_load(&S[j], __ATOMIC_RELAXED,
                                   __HIP_MEMORY_SCOPE_AGENT) * inv;
    }

    float* outb = out + (size_t)b * PTRI;
#pragma unroll
    for (int m = 0; m < 4; ++m) {
        const int ibase = i0 + r0 + 16 * m + 4 * lq;
        float di_[4], ai_[4]; int ib_[4];
#pragma unroll
        for (int r = 0; r < 4; ++r) {
            int i = ibase + r;
            di_[r] = dn[i];
            ai_[r] = gmean - __hip_atomic_load(&S[i], __ATOMIC_RELAXED,
                                               __HIP_MEMORY_SCOPE_AGENT) * inv;
            ib_[r] = i * DIM - (i * (i - 1)) / 2 - i;   // triu row offset minus i
        }
#pragma unroll
        for (int n = 0; n < 4; ++n)
#pragma unroll
            for (int p = 0; p < 4; ++p) {
                float v = __builtin_amdgcn_sqrtf(
                    fmaf(scale, fmaxf(fmaf(-2.f, acc[m][n][p], di_[p] + dj[n]), 0.f), EPSV));
                if (!pred || jj[n] >= ibase + p)
                    outb[ib_[p] + jj[n]] = v + ai_[p] + bj[n];
            }
    }
}

extern "C" void kernel_launch(void* const* d_in, const int* in_sizes, int n_in,
                              void* d_out, int out_size, void* d_ws, size_t ws_size,
                              hipStream_t stream) {
    const float* x = (const float*)d_in[0];
    const float* t = (const float*)d_in[1];
    float* out = (float*)d_out;
    float* ws  = (float*)d_ws;   // needs ~10.8 MB (see layout at top)

    k_prep<<<dim3(BATCH * DIM / 16), 256, 0, stream>>>(x, ws);
    k_main<<<dim3(NBLK2),            256, 0, stream>>>(t, ws, out);
}

// Round 8
// 114.163 us; speedup vs baseline: 2.4427x; 2.4427x over previous
//
#include <hip/hip_runtime.h>
#include <math.h>

#define BATCH 64
#define DIM   640
#define MSP   100        // spatial M = 10*10
#define TILE  64         // k_write tile
#define NT    10         // DIM / TILE
#define NPAIR 55         // 64-tile upper-tri pairs
#define BT    128        // k_sums tile
#define NT2   5          // DIM / BT
#define NPAIR2 15        // 128-tile upper-tri pairs
#define NBLK2 960        // NPAIR2 * BATCH
#define PTRI  205120     // DIM*(DIM+1)/2
#define EPSV  1e-5f

// ws float-region offsets (floats)
#define WS_D 0
#define WS_S 40960
#define WS_G 81920            // 64 grand accumulators (raw sums)
// byte offsets (float region ends at 81984*4 = 327936, 256B-aligned)
#define XB_OFF 327936ull      // swizzled bf16 x: 2560 panels x 2048 shorts = 10,485,760 B
// total ws ~10.8 MB
//
// Lessons encoded here (R0..R7):
//  - cooperative launch / host API inside kernel_launch breaks graph capture (R3/R4)
//  - device spin barriers + agent-scope atomics are latency-poisoned (R7: 2.2x)
//  - XCD-pinning batches (bid&7=XCD, 8 batches/XCD -> 1.28MB < 4MB L2) is worth
//    ~17 us (R1->R2); tile round-trip == recompute once reads are L2 hits
//  - all sane structures plateau at 123-125 us; ~52 us is harness-fixed
//    (256MiB ws poison + out memset)
//
// R8 = best-of-each-pass: k_prep + k_sums(128-tile, fewest blocks/atomics)
//      + k_write(64-tile, most parallel write pass) with below-diagonal wave
//      early-exit on diagonal tiles.

typedef __attribute__((ext_vector_type(8))) short short8;
typedef __attribute__((ext_vector_type(4))) float f32x4;

__device__ __forceinline__ short f2bf(float f) {
    union { float f; unsigned u; } x; x.f = f;
    unsigned r = x.u + 0x7fffu + ((x.u >> 16) & 1u);
    return (short)(r >> 16);
}
__device__ __forceinline__ float bf2f(short h) {
    union { unsigned u; float f; } x; x.u = ((unsigned)(unsigned short)h) << 16;
    return x.f;
}

// pair index -> (ti,tj) upper triangle, generic NT_
template <int NT_>
__device__ __forceinline__ void decode_pairN(int u, int& ti, int& tj) {
    ti = 0;
    while (u >= NT_ - ti) { u -= NT_ - ti; ++ti; }
    tj = ti + u;
}

// bid (0..959) -> (b, ti, tj), 128-tiles, XCD-pinned batches
__device__ __forceinline__ void decode_block128(int bid, int& b, int& ti, int& tj) {
    const int xcd = bid & 7;
    const int idx = bid >> 3;          // 0..119
    b = xcd + 8 * (idx & 7);           // fixed set of 8 batches per XCD
    decode_pairN<NT2>(idx >> 3, ti, tj);
}

// bid (0..3519) -> (b, ti, tj), 64-tiles, XCD-pinned batches
__device__ __forceinline__ void decode_block64(int bid, int& b, int& ti, int& tj) {
    const int xcd = bid & 7;
    const int idx = bid >> 3;          // 0..439
    b = xcd + 8 * (idx & 7);
    decode_pairN<NT>(idx >> 3, ti, tj);
}

// One pass over x: bf16 RNE convert, K 100->128 zero-pad, store SWIZZLED xb;
// norms from ROUNDED values (diag d_i+d_i-2G_ii cancels exactly vs bf16 MFMA);
// zero S and G accumulators (ws is poisoned each call).
// xb swizzle: panel = 16 rows x 128 k, stored [c = ks*4+lq][lm = row%16][8 halves].
__global__ __launch_bounds__(256) void k_prep(const float* __restrict__ x,
                                              float* __restrict__ ws) {
    short* xb = (short*)((char*)ws + XB_OFF);
    const int t = threadIdx.x;
    const int rr = t >> 4, c = t & 15;             // rr = row-in-panel, c = k-chunk
    const int row = blockIdx.x * 16 + rr;          // 0..40959
    const int k0 = c * 8;
    const float* src = x + (size_t)row * MSP;

    float v[8];
#pragma unroll
    for (int e = 0; e < 8; ++e) v[e] = 0.f;
    if (k0 <= 88) {                                // k0..k0+7 all < 100
        float4 u0 = *(const float4*)(src + k0);
        float4 u1 = *(const float4*)(src + k0 + 4);
        v[0] = u0.x; v[1] = u0.y; v[2] = u0.z; v[3] = u0.w;
        v[4] = u1.x; v[5] = u1.y; v[6] = u1.z; v[7] = u1.w;
    } else if (k0 == 96) {                         // only 96..99 valid (no OOB read)
        float4 u0 = *(const float4*)(src + 96);
        v[0] = u0.x; v[1] = u0.y; v[2] = u0.z; v[3] = u0.w;
    }

    short8 h; float s = 0.f;
#pragma unroll
    for (int e = 0; e < 8; ++e) {
        short hb = f2bf(v[e]);
        float vr = bf2f(hb);
        s += vr * vr;
        h[e] = hb;
    }
    // swizzled store: panel base + c*128 + rr*8
    *(short8*)(xb + (size_t)blockIdx.x * 2048 + c * 128 + rr * 8) = h;

    // norm reduce over the 16 k-chunks (lanes with same rr, c = lane&15)
    s += __shfl_xor(s, 1); s += __shfl_xor(s, 2);
    s += __shfl_xor(s, 4); s += __shfl_xor(s, 8);
    if (c == 0) { ws[WS_D + row] = s; ws[WS_S + row] = 0.f; }
    if (blockIdx.x == 0 && t < BATCH) ws[WS_G + t] = 0.f;
}

// Pass 1: 128x128 tile (960 blocks). Wave (wr,wc) owns a 64x64 quadrant with
// acc[4][4] -> sqrt-dcov -> S (row sums + symmetric col fold) + grand sum.
__global__ __launch_bounds__(256) void k_sums(const float* __restrict__ tsc,
                                              float* __restrict__ ws) {
    __shared__ float sRow[BT];
    __shared__ float sCol[BT];

    int b, ti, tj;
    decode_block128(blockIdx.x, b, ti, tj);
    const int i0 = ti * BT, j0 = tj * BT;
    const int tid = threadIdx.x;
    const short* xb = (const short*)((const char*)ws + XB_OFF);

    if (tid < BT) { sRow[tid] = 0.f; sCol[tid] = 0.f; }

    const int wave = tid >> 6, lane = tid & 63;
    const int lm = lane & 15, lq = lane >> 4;
    const int r0 = (wave >> 1) * 64, c0 = (wave & 1) * 64;

    // per-lane frag pointers; panel m at +m*2048, k-step ks at +ks*512
    const short* pa = xb + (size_t)(b * 40 + ((i0 + r0) >> 4)) * 2048 + lq * 128 + lm * 8;
    const short* pb = xb + (size_t)(b * 40 + ((j0 + c0) >> 4)) * 2048 + lq * 128 + lm * 8;

    f32x4 acc[4][4] = {};
#pragma unroll
    for (int ks = 0; ks < 4; ++ks) {
        short8 af[4], bf[4];
#pragma unroll
        for (int m = 0; m < 4; ++m) af[m] = *(const short8*)(pa + m * 2048 + ks * 512);
#pragma unroll
        for (int n = 0; n < 4; ++n) bf[n] = *(const short8*)(pb + n * 2048 + ks * 512);
#pragma unroll
        for (int m = 0; m < 4; ++m)
#pragma unroll
            for (int n = 0; n < 4; ++n)
                acc[m][n] = __builtin_amdgcn_mfma_f32_16x16x32_bf16(af[m], bf[n], acc[m][n], 0, 0, 0);
    }

    const float scale = expf(tsc[0]);
    const float* dn = ws + WS_D + b * DIM;
    float dj[4];
#pragma unroll
    for (int n = 0; n < 4; ++n) dj[n] = dn[j0 + c0 + 16 * n + lm];

    float rp[4][4] = {}, cp[4] = {};
#pragma unroll
    for (int m = 0; m < 4; ++m) {
        float di_[4];
#pragma unroll
        for (int r = 0; r < 4; ++r) di_[r] = dn[i0 + r0 + 16 * m + 4 * lq + r];
#pragma unroll
        for (int n = 0; n < 4; ++n)
#pragma unroll
            for (int p = 0; p < 4; ++p) {
                float v = __builtin_amdgcn_sqrtf(
                    fmaf(scale, fmaxf(fmaf(-2.f, acc[m][n][p], di_[p] + dj[n]), 0.f), EPSV));
                rp[m][p] += v; cp[n] += v;
            }
    }

    __syncthreads();   // sRow/sCol zero-init visible before LDS atomics
#pragma unroll
    for (int m = 0; m < 4; ++m)
#pragma unroll
        for (int p = 0; p < 4; ++p) {
            float v = rp[m][p];
            v += __shfl_xor(v, 1); v += __shfl_xor(v, 2);
            v += __shfl_xor(v, 4); v += __shfl_xor(v, 8);
            if (lm == 0) atomicAdd(&sRow[r0 + 16 * m + 4 * lq + p], v);
        }
#pragma unroll
    for (int n = 0; n < 4; ++n) {
        float v = cp[n];
        v += __shfl_xor(v, 16); v += __shfl_xor(v, 32);
        if (lq == 0) atomicAdd(&sCol[c0 + 16 * n + lm], v);
    }
    __syncthreads();

    float* S = ws + WS_S + b * DIM;
    if (tid < BT) {
        atomicAdd(&S[i0 + tid], sRow[tid]);
        if (ti != tj) atomicAdd(&S[j0 + tid], sCol[tid]);  // symmetry: col==row sums
        float gg = sRow[tid];                              // per-batch grand (raw)
        gg += __shfl_xor(gg, 1);  gg += __shfl_xor(gg, 2);  gg += __shfl_xor(gg, 4);
        gg += __shfl_xor(gg, 8);  gg += __shfl_xor(gg, 16); gg += __shfl_xor(gg, 32);
        if (lane == 0) atomicAdd(&ws[WS_G + b], (ti == tj ? 1.f : 2.f) * gg);
    }
}

// Pass 2: 64-tile (3520 blocks), RECOMPUTE quadrant (frag reads = L2 hits),
// center, write triu fp32. Diagonal tiles: the below-diagonal wave quadrant
// (r0=32,c0=0) returns before any work. No LDS/barriers in this kernel.
__global__ __launch_bounds__(256) void k_write(const float* __restrict__ tsc,
                                               const float* __restrict__ ws,
                                               float* __restrict__ out) {
    int b, ti, tj;
    decode_block64(blockIdx.x, b, ti, tj);
    const int i0 = ti * TILE, j0 = tj * TILE;
    const int tid = threadIdx.x;
    const short* xb = (const short*)((const char*)ws + XB_OFF);

    const int wave = tid >> 6, lane = tid & 63;
    const int lm = lane & 15, lq = lane >> 4;
    const int wr = wave >> 1, wc = wave & 1;
    const int r0 = wr * 32, c0 = wc * 32;

    const bool diag = (ti == tj);
    if (diag && wr > wc) return;       // 32x32 quadrant fully below diagonal
    const bool pred = diag && (wr == wc);

    const short* pa = xb + (size_t)(b * 40 + ((i0 + r0) >> 4)) * 2048 + lq * 128 + lm * 8;
    const short* pb = xb + (size_t)(b * 40 + ((j0 + c0) >> 4)) * 2048 + lq * 128 + lm * 8;

    f32x4 acc[2][2] = {};
#pragma unroll
    for (int ks = 0; ks < 4; ++ks) {
        short8 a0 = *(const short8*)(pa + ks * 512);
        short8 a1 = *(const short8*)(pa + 2048 + ks * 512);
        short8 b0 = *(const short8*)(pb + ks * 512);
        short8 b1 = *(const short8*)(pb + 2048 + ks * 512);
        acc[0][0] = __builtin_amdgcn_mfma_f32_16x16x32_bf16(a0, b0, acc[0][0], 0, 0, 0);
        acc[0][1] = __builtin_amdgcn_mfma_f32_16x16x32_bf16(a0, b1, acc[0][1], 0, 0, 0);
        acc[1][0] = __builtin_amdgcn_mfma_f32_16x16x32_bf16(a1, b0, acc[1][0], 0, 0, 0);
        acc[1][1] = __builtin_amdgcn_mfma_f32_16x16x32_bf16(a1, b1, acc[1][1], 0, 0, 0);
    }

    const float scale = expf(tsc[0]);
    const float inv = 1.f / (float)DIM;
    const float g = ws[WS_G + b] * (inv * inv);
    const float* S  = ws + WS_S + b * DIM;
    const float* dn = ws + WS_D + b * DIM;

    float di[2][4], ai[2][4]; int ib[2][4];
#pragma unroll
    for (int a = 0; a < 2; ++a)
#pragma unroll
        for (int r = 0; r < 4; ++r) {
            int i = i0 + r0 + 16 * a + 4 * lq + r;
            di[a][r] = dn[i];
            ai[a][r] = g - S[i] * inv;
            ib[a][r] = i * DIM - (i * (i - 1)) / 2 - i;   // triu row offset minus i
        }
    float dj[2], bj[2]; int jj[2];
#pragma unroll
    for (int bb = 0; bb < 2; ++bb) {
        int j = j0 + c0 + 16 * bb + lm;
        jj[bb] = j; dj[bb] = dn[j]; bj[bb] = -S[j] * inv;
    }

    float* outb = out + (size_t)b * PTRI;
#pragma unroll
    for (int a = 0; a < 2; ++a) {
        const int ibase = i0 + r0 + 16 * a + 4 * lq;
#pragma unroll
        for (int bb = 0; bb < 2; ++bb)
#pragma unroll
            for (int p = 0; p < 2; ++p) {
                const int r = 2 * p;
                float d0 = di[a][r]     + dj[bb];
                float d1 = di[a][r + 1] + dj[bb];
                float v0 = __builtin_amdgcn_sqrtf(
                    fmaf(scale, fmaxf(fmaf(-2.f, acc[a][bb][r],     d0), 0.f), EPSV));
                float v1 = __builtin_amdgcn_sqrtf(
                    fmaf(scale, fmaxf(fmaf(-2.f, acc[a][bb][r + 1], d1), 0.f), EPSV));
                if (!pred || jj[bb] >= ibase + r)
                    outb[ib[a][r]     + jj[bb]] = v0 + ai[a][r]     + bj[bb];
                if (!pred || jj[bb] >= ibase + r + 1)
                    outb[ib[a][r + 1] + jj[bb]] = v1 + ai[a][r + 1] + bj[bb];
            }
    }
}

extern "C" void kernel_launch(void* const* d_in, const int* in_sizes, int n_in,
                              void* d_out, int out_size, void* d_ws, size_t ws_size,
                              hipStream_t stream) {
    const float* x = (const float*)d_in[0];
    const float* t = (const float*)d_in[1];
    float* out = (float*)d_out;
    float* ws  = (float*)d_ws;   // needs ~10.8 MB (see layout at top)

    k_prep <<<dim3(BATCH * DIM / 16), 256, 0, stream>>>(x, ws);
    k_sums <<<dim3(NBLK2),            256, 0, stream>>>(t, ws);
    k_write<<<dim3(NPAIR * BATCH),    256, 0, stream>>>(t, ws, out);
}